// Round 1
// baseline (805.942 us; speedup 1.0000x reference)
//
#include <hip/hip_runtime.h>
#include <hip/hip_bf16.h>

#define TS 20
#define DNUM 128
#define HH 256
#define NWORDS 16384
#define WPB 64                    // words per block
#define NB_PER_DIR (NWORDS / WPB) // 256

typedef __attribute__((ext_vector_type(8))) short s8v;
typedef __attribute__((ext_vector_type(4))) float f4v;

__device__ __forceinline__ unsigned short bf16_rne(float f) {
  union { float f; unsigned u; } x; x.f = f;
  unsigned r = x.u + 0x7fffu + ((x.u >> 16) & 1u);
  return (unsigned short)(r >> 16);
}

// tab[dir][c][j] = b_in[j] + sum_d emb[c][d] * Wk[d][j]   (f32, exact-ish)
__global__ void build_tab(const float* __restrict__ emb,
                          const float* __restrict__ wkF, const float* __restrict__ bF,
                          const float* __restrict__ wkB, const float* __restrict__ bB,
                          float* __restrict__ tab) {
  int gid = blockIdx.x * 256 + threadIdx.x;
  if (gid >= 2 * 129 * 768) return;
  int dir = gid / (129 * 768);
  int rem = gid - dir * (129 * 768);
  int c = rem / 768, j = rem - (rem / 768) * 768;
  const float* Wk = dir ? wkB : wkF;
  const float* bb = dir ? bB : bF;
  float s = bb[j];                       // b[0] row = input bias
  const float* er = emb + c * DNUM;
  #pragma unroll 4
  for (int d = 0; d < DNUM; ++d) s = fmaf(er[d], Wk[d * 768 + j], s);
  tab[gid] = s;
}

// Pack Wr (f32 [256][768]) into bf16 MFMA-B-fragment order:
// wp[dir][((ct*8+kk)*64+lane)] = 8 bf16: Wr[kk*32+(lane>>4)*8+e][ct*16+(lane&15)]
__global__ void pack_wr(const float* __restrict__ wrF, const float* __restrict__ wrB,
                        uint4* __restrict__ wp) {
  int gid = blockIdx.x * 256 + threadIdx.x;
  if (gid >= 2 * 48 * 8 * 64) return;
  int dir = gid / (48 * 8 * 64);
  int rem = gid - dir * (48 * 8 * 64);
  int ct = rem / (8 * 64);
  int kk = (rem / 64) & 7;
  int lane = rem & 63;
  const float* Wr = dir ? wrB : wrF;
  int n = ct * 16 + (lane & 15);
  int k0 = kk * 32 + (lane >> 4) * 8;
  union { unsigned short v[8]; uint4 q; } u;
  #pragma unroll
  for (int e = 0; e < 8; ++e) u.v[e] = bf16_rne(Wr[(k0 + e) * 768 + n]);
  wp[gid] = u.q;
}

// Persistent GRU: block = 64 words x 1 direction, loops T=20 steps.
// hg = h @ Wr via mfma_f32_16x16x32_bf16; h master state in f32 regs
// (distribution == C/D layout), bf16 copy in LDS (double-buffered) as A-operand.
__global__ __launch_bounds__(512, 2) void gru_main(
    const int* __restrict__ chars, const float* __restrict__ tab,
    const uint4* __restrict__ wrp, const float* __restrict__ bf_,
    const float* __restrict__ bb_, float* __restrict__ out) {
  const int bid = blockIdx.x;
  const int dir = bid >> 8;            // 256 blocks per direction
  const int wb = bid & 255;
  const int word0 = wb * WPB;
  const float* table = tab + dir * (129 * 768);
  const uint4* WP = wrp + dir * (48 * 8 * 64);
  const float* brec = (dir ? bb_ : bf_) + 768;   // b[1] row = recurrent bias

  const int tid = threadIdx.x;
  const int wave = tid >> 6, lane = tid & 63;
  const int lr = lane >> 4, lc = lane & 15;
  const int ui0 = wave * 2;            // this wave's 2 unit-tiles (of 16)

  __shared__ unsigned short hbf[2][WPB][HH + 8];   // +8 pad: 528B stride -> 2-way banks
  __shared__ int sch[WPB * TS];

  for (int i = tid; i < WPB * TS; i += 512) sch[i] = chars[word0 * TS + i];
  for (int i = tid; i < WPB * (HH + 8); i += 512) (&hbf[0][0][0])[i] = 0;

  float h[4][2][4];
  #pragma unroll
  for (int mi = 0; mi < 4; ++mi)
    #pragma unroll
    for (int ui = 0; ui < 2; ++ui)
      #pragma unroll
      for (int r = 0; r < 4; ++r) h[mi][ui][r] = 0.f;

  float br[2][3];
  #pragma unroll
  for (int ui = 0; ui < 2; ++ui)
    #pragma unroll
    for (int g = 0; g < 3; ++g) br[ui][g] = brec[g * 256 + (ui0 + ui) * 16 + lc];

  __syncthreads();

  int cur = 0;
  #pragma unroll 1
  for (int t = 0; t < TS; ++t) {
    const int ts = dir ? (TS - 1 - t) : t;     // backward sees reversed sequence

    f4v acc[4][2][3];
    const f4v z4 = {0.f, 0.f, 0.f, 0.f};
    #pragma unroll
    for (int mi = 0; mi < 4; ++mi)
      #pragma unroll
      for (int ui = 0; ui < 2; ++ui)
        #pragma unroll
        for (int g = 0; g < 3; ++g) acc[mi][ui][g] = z4;

    #pragma unroll
    for (int kk = 0; kk < 8; ++kk) {
      uint4 a[4];
      #pragma unroll
      for (int mi = 0; mi < 4; ++mi)
        a[mi] = *(const uint4*)&hbf[cur][mi * 16 + lc][kk * 32 + lr * 8];
      uint4 b[2][3];
      #pragma unroll
      for (int ui = 0; ui < 2; ++ui)
        #pragma unroll
        for (int g = 0; g < 3; ++g)
          b[ui][g] = WP[((g * 16 + ui0 + ui) * 8 + kk) * 64 + lane];
      #pragma unroll
      for (int mi = 0; mi < 4; ++mi)
        #pragma unroll
        for (int ui = 0; ui < 2; ++ui)
          #pragma unroll
          for (int g = 0; g < 3; ++g)
            acc[mi][ui][g] = __builtin_amdgcn_mfma_f32_16x16x32_bf16(
                __builtin_bit_cast(s8v, a[mi]),
                __builtin_bit_cast(s8v, b[ui][g]),
                acc[mi][ui][g], 0, 0, 0);
    }

    const int nxt = cur ^ 1;
    #pragma unroll
    for (int mi = 0; mi < 4; ++mi) {
      #pragma unroll
      for (int r = 0; r < 4; ++r) {
        const int lw = mi * 16 + lr * 4 + r;       // local word (== C/D row)
        const int c = sch[lw * TS + ts];
        const float* trow = table + c * 768;
        #pragma unroll
        for (int ui = 0; ui < 2; ++ui) {
          const int u = (ui0 + ui) * 16 + lc;      // unit (== C/D col)
          float xz = trow[u];
          float xr = trow[256 + u];
          float xh = trow[512 + u];
          float hz = acc[mi][ui][0][r] + br[ui][0];
          float hr = acc[mi][ui][1][r] + br[ui][1];
          float hh2 = acc[mi][ui][2][r] + br[ui][2];
          float z = 1.f / (1.f + __expf(-(xz + hz)));
          float rr = 1.f / (1.f + __expf(-(xr + hr)));
          float y = xh + rr * hh2;
          float hc = 1.f - 2.f / (1.f + __expf(2.f * y));   // tanh(y)
          float hp = h[mi][ui][r];
          float hn = z * hp + (1.f - z) * hc;
          hn = (c != 0) ? hn : hp;                 // masked step: pass-through
          h[mi][ui][r] = hn;
          hbf[nxt][lw][u] = bf16_rne(hn);
        }
      }
    }
    __syncthreads();
    cur = nxt;
  }

  #pragma unroll
  for (int mi = 0; mi < 4; ++mi)
    #pragma unroll
    for (int ui = 0; ui < 2; ++ui)
      #pragma unroll
      for (int r = 0; r < 4; ++r) {
        const int lw = mi * 16 + lr * 4 + r;
        const int u = (ui0 + ui) * 16 + lc;
        out[(size_t)(word0 + lw) * 512 + dir * 256 + u] = h[mi][ui][r];
      }
}

extern "C" void kernel_launch(void* const* d_in, const int* in_sizes, int n_in,
                              void* d_out, int out_size, void* d_ws, size_t ws_size,
                              hipStream_t stream) {
  const int* chars = (const int*)d_in[0];
  const float* emb = (const float*)d_in[1];
  const float* wkF = (const float*)d_in[2];
  const float* wrF = (const float*)d_in[3];
  const float* bF  = (const float*)d_in[4];
  const float* wkB = (const float*)d_in[5];
  const float* wrB = (const float*)d_in[6];
  const float* bB  = (const float*)d_in[7];
  float* outp = (float*)d_out;

  float* tab = (float*)d_ws;                              // 2*129*768 f32 = 792576 B
  uint4* wrp = (uint4*)((char*)d_ws + 2 * 129 * 768 * 4); // 2*48*8*64 uint4 = 786432 B

  build_tab<<<(2 * 129 * 768 + 255) / 256, 256, 0, stream>>>(emb, wkF, bF, wkB, bB, tab);
  pack_wr<<<(2 * 48 * 8 * 64 + 255) / 256, 256, 0, stream>>>(wrF, wrB, wrp);
  gru_main<<<2 * NB_PER_DIR, 512, 0, stream>>>(chars, tab, wrp, bF, bB, outp);
}

// Round 2
// 569.325 us; speedup vs baseline: 1.4156x; 1.4156x over previous
//
#include <hip/hip_runtime.h>
#include <hip/hip_bf16.h>

#define TS 20
#define DNUM 128
#define HH 256
#define NWORDS 16384
#define WPB 64                      // words per block
#define NBLK (2 * NWORDS / WPB)     // 512 blocks (fwd + bwd)

typedef __attribute__((ext_vector_type(8))) short s8v;
typedef __attribute__((ext_vector_type(4))) float f4v;

__device__ __forceinline__ unsigned short bf16_rne(float f) {
  union { float f; unsigned u; } x; x.f = f;
  unsigned r = x.u + 0x7fffu + ((x.u >> 16) & 1u);
  return (unsigned short)(r >> 16);
}

// tab4[dir][c][u] = float4(xz, xr, xh, unused): b_in + emb[c] @ Wk, f32.
__global__ void build_tab4(const float* __restrict__ emb,
                           const float* __restrict__ wkF, const float* __restrict__ bF,
                           const float* __restrict__ wkB, const float* __restrict__ bB,
                           float* __restrict__ tab4) {
  int gid = blockIdx.x * 256 + threadIdx.x;
  if (gid >= 2 * 129 * 768) return;
  int dir = gid / (129 * 768);
  int rem = gid - dir * (129 * 768);
  int c = rem / 768, j = rem - (rem / 768) * 768;
  int g = j >> 8, u = j & 255;
  const float* Wk = dir ? wkB : wkF;
  const float* bb = dir ? bB : bF;
  float s = bb[j];                       // b[0] row = input bias
  const float* er = emb + c * DNUM;
  #pragma unroll 4
  for (int d = 0; d < DNUM; ++d) s = fmaf(er[d], Wk[d * 768 + j], s);
  tab4[((((size_t)dir * 129) + c) * 256 + u) * 4 + g] = s;
}

// Pack Wr (f32 [256][768]) into bf16 MFMA-B-fragment order (verified round 1):
// wp[dir][((ct*8+kk)*64+lane)] = 8 bf16: Wr[kk*32+(lane>>4)*8+e][ct*16+(lane&15)]
__global__ void pack_wr(const float* __restrict__ wrF, const float* __restrict__ wrB,
                        uint4* __restrict__ wp) {
  int gid = blockIdx.x * 256 + threadIdx.x;
  if (gid >= 2 * 48 * 8 * 64) return;
  int dir = gid / (48 * 8 * 64);
  int rem = gid - dir * (48 * 8 * 64);
  int ct = rem / (8 * 64);
  int kk = (rem / 64) & 7;
  int lane = rem & 63;
  const float* Wr = dir ? wrB : wrF;
  int n = ct * 16 + (lane & 15);
  int k0 = kk * 32 + (lane >> 4) * 8;
  union { unsigned short v[8]; uint4 q; } u;
  #pragma unroll
  for (int e = 0; e < 8; ++e) u.v[e] = bf16_rne(Wr[(k0 + e) * 768 + n]);
  wp[gid] = u.q;
}

// Persistent GRU: block = 64 words x 1 direction, 1024 threads (16 waves),
// wave = 1 unit-tile x 3 gates x 4 m-tiles. h master state f32 in regs
// (C/D layout), bf16 copy in LDS (double-buffered) as MFMA A-operand.
__global__ __launch_bounds__(1024, 4) void gru_main(
    const int* __restrict__ chars, const float* __restrict__ tab4,
    const uint4* __restrict__ wrp, const float* __restrict__ bf_,
    const float* __restrict__ bb_, float* __restrict__ out) {
  const int bid = blockIdx.x;
  const int dir = bid >> 8;            // 256 blocks per direction
  const int wb = bid & 255;
  const int word0 = wb * WPB;
  const float4* table = (const float4*)tab4 + (size_t)dir * 129 * 256;
  const uint4* WP = wrp + dir * (48 * 8 * 64);
  const float* brec = (dir ? bb_ : bf_) + 768;   // b[1] row = recurrent bias

  const int tid = threadIdx.x;
  const int w = tid >> 6, lane = tid & 63;
  const int lr = lane >> 4, lc = lane & 15;
  const int u = w * 16 + lc;           // this thread's single output unit

  __shared__ unsigned short hbf[2][WPB][HH + 8];   // 528B stride: A-reads conflict-free
  __shared__ int sch[WPB * TS];

  for (int i = tid; i < WPB * TS; i += 1024) sch[i] = chars[word0 * TS + i];
  for (int i = tid; i < WPB * (HH + 8); i += 1024) (&hbf[0][0][0])[i] = 0;

  float h[16];
  #pragma unroll
  for (int i = 0; i < 16; ++i) h[i] = 0.f;

  const float br0 = brec[0 * 256 + u];
  const float br1 = brec[1 * 256 + u];
  const float br2 = brec[2 * 256 + u];
  const float L2E = 1.4426950408889634f;

  __syncthreads();

  int cur = 0;
  #pragma unroll 1
  for (int t = 0; t < TS; ++t) {
    const int ts = dir ? (TS - 1 - t) : t;     // backward: reversed sequence

    f4v acc[4][3];
    const f4v z4 = {0.f, 0.f, 0.f, 0.f};
    #pragma unroll
    for (int mi = 0; mi < 4; ++mi)
      #pragma unroll
      for (int g = 0; g < 3; ++g) acc[mi][g] = z4;

    #pragma unroll
    for (int kk = 0; kk < 8; ++kk) {
      uint4 a[4];
      #pragma unroll
      for (int mi = 0; mi < 4; ++mi)
        a[mi] = *(const uint4*)&hbf[cur][mi * 16 + lc][kk * 32 + lr * 8];
      uint4 b[3];
      #pragma unroll
      for (int g = 0; g < 3; ++g)
        b[g] = WP[((g * 16 + w) * 8 + kk) * 64 + lane];
      #pragma unroll
      for (int mi = 0; mi < 4; ++mi)
        #pragma unroll
        for (int g = 0; g < 3; ++g)
          acc[mi][g] = __builtin_amdgcn_mfma_f32_16x16x32_bf16(
              __builtin_bit_cast(s8v, a[mi]),
              __builtin_bit_cast(s8v, b[g]),
              acc[mi][g], 0, 0, 0);
    }

    const int nxt = cur ^ 1;

    // Epilogue: per-m-tile staggered xg prefetch (one 16B load per output).
    float4 xgA[4], xgB[4];
    int ccA[4], ccB[4];
    #pragma unroll
    for (int r = 0; r < 4; ++r) {                 // prefetch mi=0 -> A
      const int lw = lr * 4 + r;
      const int c = sch[lw * TS + ts];
      ccA[r] = c;
      xgA[r] = table[c * 256 + u];
    }
    #pragma unroll
    for (int mi = 0; mi < 4; ++mi) {
      if (mi < 3) {                               // prefetch mi+1 -> other buf
        #pragma unroll
        for (int r = 0; r < 4; ++r) {
          const int lw = (mi + 1) * 16 + lr * 4 + r;
          const int c = sch[lw * TS + ts];
          if (mi & 1) { ccA[r] = c; xgA[r] = table[c * 256 + u]; }
          else        { ccB[r] = c; xgB[r] = table[c * 256 + u]; }
        }
      }
      #pragma unroll
      for (int r = 0; r < 4; ++r) {
        const int lw = mi * 16 + lr * 4 + r;
        const float4 xg = (mi & 1) ? xgB[r] : xgA[r];
        const int c = (mi & 1) ? ccB[r] : ccA[r];
        const float hz = acc[mi][0][r] + br0;
        const float hr = acc[mi][1][r] + br1;
        const float hh2 = acc[mi][2][r] + br2;
        const float z = __builtin_amdgcn_rcpf(
            1.f + __builtin_amdgcn_exp2f(-(xg.x + hz) * L2E));
        const float rr = __builtin_amdgcn_rcpf(
            1.f + __builtin_amdgcn_exp2f(-(xg.y + hr) * L2E));
        const float y = fmaf(rr, hh2, xg.z);
        const float hc = fmaf(-2.f, __builtin_amdgcn_rcpf(
            1.f + __builtin_amdgcn_exp2f(y * (2.f * L2E))), 1.f);
        const float hp = h[mi * 4 + r];
        float hn = fmaf(1.f - z, hc - hp, hp);
        hn = (c != 0) ? hn : hp;                 // masked step: pass-through
        h[mi * 4 + r] = hn;
        hbf[nxt][lw][u] = bf16_rne(hn);
      }
    }
    __syncthreads();
    cur = nxt;
  }

  #pragma unroll
  for (int mi = 0; mi < 4; ++mi)
    #pragma unroll
    for (int r = 0; r < 4; ++r) {
      const int lw = mi * 16 + lr * 4 + r;
      out[(size_t)(word0 + lw) * 512 + dir * 256 + u] = h[mi * 4 + r];
    }
}

extern "C" void kernel_launch(void* const* d_in, const int* in_sizes, int n_in,
                              void* d_out, int out_size, void* d_ws, size_t ws_size,
                              hipStream_t stream) {
  const int* chars = (const int*)d_in[0];
  const float* emb = (const float*)d_in[1];
  const float* wkF = (const float*)d_in[2];
  const float* wrF = (const float*)d_in[3];
  const float* bF  = (const float*)d_in[4];
  const float* wkB = (const float*)d_in[5];
  const float* wrB = (const float*)d_in[6];
  const float* bB  = (const float*)d_in[7];
  float* outp = (float*)d_out;

  float* tab4 = (float*)d_ws;                               // 2*129*256*16B = 1056768 B
  uint4* wrp = (uint4*)((char*)d_ws + 2 * 129 * 256 * 16);  // 2*48*8*64*16B = 786432 B

  build_tab4<<<(2 * 129 * 768 + 255) / 256, 256, 0, stream>>>(emb, wkF, bF, wkB, bB, tab4);
  pack_wr<<<(2 * 48 * 8 * 64 + 255) / 256, 256, 0, stream>>>(wrF, wrB, wrp);
  gru_main<<<NBLK, 1024, 0, stream>>>(chars, tab4, wrp, bF, bB, outp);
}